// Round 1
// baseline (1498.761 us; speedup 1.0000x reference)
//
#include <hip/hip_runtime.h>

#define B_   64
#define C_   256
#define N_   20000
#define NT_  64
#define K_   8
#define TOK_FLOATS (B_ * K_ * NT_ * C_)   // 8388608

typedef __attribute__((ext_vector_type(8))) short short8;
typedef __attribute__((ext_vector_type(4))) float floatx4;

static __device__ __forceinline__ unsigned short f2bf(float f) {
    unsigned int x = __builtin_bit_cast(unsigned int, f);
    x += 0x7fffu + ((x >> 16) & 1u);           // RNE
    return (unsigned short)(x >> 16);
}

// ---------------- K0: W fp32 -> bf16 (row-major, same layout) ----------------
__global__ __launch_bounds__(256) void k_wconv(const float* __restrict__ w,
                                               unsigned short* __restrict__ wbf) {
    int i = blockIdx.x * 256 + threadIdx.x;    // 16384 threads * 4 elems
    float4 v = ((const float4*)w)[i];
    ushort4 o;
    o.x = f2bf(v.x); o.y = f2bf(v.y); o.z = f2bf(v.z); o.w = f2bf(v.w);
    ((ushort4*)wbf)[i] = o;
}

// ---------------- K1: sims[b][n] = dot(q_b, s_n) / ||s_n|| (fp32) ------------
// Block: 256 threads = 8 b-groups x 32 n-groups; thread computes 8 b x 4 n.
// Grid: 157 blocks x 128 n.
__global__ __launch_bounds__(256) void k_sims(const float* __restrict__ q,
                                              const float* __restrict__ s,
                                              float* __restrict__ sims) {
    __shared__ float Q[B_ * C_];               // 64 KB
    int t = threadIdx.x;
    {
        const float4* q4 = (const float4*)q;
        float4* Q4 = (float4*)Q;
        #pragma unroll
        for (int i = 0; i < 16; i++) Q4[t + 256 * i] = q4[t + 256 * i];
    }
    __syncthreads();

    int bg = t >> 5;                           // 0..7
    int ng = t & 31;                           // 0..31
    int n_base = blockIdx.x * 128 + ng * 4;

    const float* srow[4];
    #pragma unroll
    for (int j = 0; j < 4; j++) {
        int r = n_base + j;
        if (r > N_ - 1) r = N_ - 1;
        srow[j] = s + (size_t)r * C_;
    }

    float acc[8][4];
    #pragma unroll
    for (int i = 0; i < 8; i++)
        #pragma unroll
        for (int j = 0; j < 4; j++) acc[i][j] = 0.0f;
    float ss[4] = {0.f, 0.f, 0.f, 0.f};

    for (int k0 = 0; k0 < C_; k0 += 4) {
        float4 sv[4];
        #pragma unroll
        for (int j = 0; j < 4; j++) {
            sv[j] = *(const float4*)(srow[j] + k0);
            ss[j] += sv[j].x * sv[j].x + sv[j].y * sv[j].y +
                     sv[j].z * sv[j].z + sv[j].w * sv[j].w;
        }
        float4 qv[8];
        #pragma unroll
        for (int i = 0; i < 8; i++)
            qv[i] = *(const float4*)&Q[(bg * 8 + i) * C_ + k0];
        #pragma unroll
        for (int i = 0; i < 8; i++)
            #pragma unroll
            for (int j = 0; j < 4; j++)
                acc[i][j] += qv[i].x * sv[j].x + qv[i].y * sv[j].y +
                             qv[i].z * sv[j].z + qv[i].w * sv[j].w;
    }

    #pragma unroll
    for (int j = 0; j < 4; j++) {
        int n = n_base + j;
        if (n < N_) {
            float inv = 1.0f / fmaxf(sqrtf(ss[j]), 1e-12f);
            #pragma unroll
            for (int i = 0; i < 8; i++)
                sims[(size_t)(bg * 8 + i) * N_ + n] = acc[i][j] * inv;
        }
    }
}

// ---------------- K2: per-row top-8 (jax tie-break: lower index first) -------
// One block per b. Also writes the gate outputs out[TOK_FLOATS + b].
__global__ __launch_bounds__(256) void k_topk(const float* __restrict__ sims,
                                              int* __restrict__ top_idx,
                                              const float* __restrict__ gl,
                                              float* __restrict__ out) {
    __shared__ float rv[256];
    __shared__ int   ri[256];
    int t = threadIdx.x;
    int b = blockIdx.x;
    const float* sb = sims + (size_t)b * N_;

    const float NEG = -3.402823466e38f;
    float tv[8]; int ti[8];
    #pragma unroll
    for (int r = 0; r < 8; r++) { tv[r] = NEG; ti[r] = 0x7fffffff; }

    for (int n = t; n < N_; n += 256) {
        float v = sb[n];
        if (v > tv[7]) {
            int p = 7;
            while (p > 0 && v > tv[p - 1]) { tv[p] = tv[p - 1]; ti[p] = ti[p - 1]; p--; }
            tv[p] = v; ti[p] = n;
        }
    }

    int head = 0;
    for (int kk = 0; kk < 8; kk++) {
        float cv = (head < 8) ? tv[head] : NEG;
        int   ci = (head < 8) ? ti[head] : 0x7fffffff;
        rv[t] = cv; ri[t] = ci;
        __syncthreads();
        for (int ofs = 128; ofs > 0; ofs >>= 1) {
            if (t < ofs) {
                float ov = rv[t + ofs]; int oi = ri[t + ofs];
                if (ov > rv[t] || (ov == rv[t] && oi < ri[t])) { rv[t] = ov; ri[t] = oi; }
            }
            __syncthreads();
        }
        float bv = rv[0]; int bi = ri[0];
        if (t == 0) top_idx[b * K_ + kk] = bi;
        if (head < 8 && cv == bv && ci == bi) head++;
        __syncthreads();
    }

    if (t == 0) {
        float g = 1.0f / (1.0f + expf(-gl[0]));
        out[TOK_FLOATS + b] = g;
    }
}

// ---------------- K3: gather + (x @ W^T + bias) + LayerNorm + gate -----------
// One block per (b, kk): 64 tokens x 256 out. 4 waves, each 16 rows x 256 cols.
__global__ __launch_bounds__(256) void k_tok(const float* __restrict__ templ,
                                             const unsigned short* __restrict__ wbf,
                                             const int* __restrict__ tidx,
                                             const float* __restrict__ bias,
                                             const float* __restrict__ gamma,
                                             const float* __restrict__ beta,
                                             const float* __restrict__ gl,
                                             float* __restrict__ out) {
    __shared__ unsigned short WS[256 * 72];    // W chunk [n=256][k=64] +8 pad (36 KB)
    __shared__ unsigned short XS[64 * 72];     // X chunk [m=64][k=64] +8 pad (9 KB)
    __shared__ float PB[256], PG[256], PE[256];

    int t = threadIdx.x;
    int bid = blockIdx.x;                      // b*8 + kk
    int idx = tidx[bid];
    const float* src = templ + (size_t)idx * (NT_ * C_);

    PB[t] = bias[t]; PG[t] = gamma[t]; PE[t] = beta[t];
    float gate = 1.0f / (1.0f + expf(-gl[0]));

    int lane = t & 63, wave = t >> 6;
    int quad = lane >> 4, c = lane & 15;
    int m_base = wave * 16;

    floatx4 acc[16];
    #pragma unroll
    for (int nt = 0; nt < 16; nt++) acc[nt] = (floatx4){0.f, 0.f, 0.f, 0.f};

    for (int k0 = 0; k0 < C_; k0 += 64) {
        __syncthreads();                        // protect prev iter's LDS reads
        // stage W chunk: 2048 x 16B
        #pragma unroll
        for (int i = 0; i < 8; i++) {
            int f = t + 256 * i;                // 0..2047
            int j = f >> 3, c8 = f & 7;
            uint4 v = *(const uint4*)(wbf + j * 256 + k0 + c8 * 8);
            *(uint4*)(&WS[j * 72 + c8 * 8]) = v;
        }
        // stage X chunk (fp32 -> bf16): 1024 x float4
        #pragma unroll
        for (int i = 0; i < 4; i++) {
            int f = t + 256 * i;                // 0..1023
            int m = f >> 4, c4 = f & 15;
            float4 v = *(const float4*)(src + m * 256 + k0 + c4 * 4);
            ushort4 o;
            o.x = f2bf(v.x); o.y = f2bf(v.y); o.z = f2bf(v.z); o.w = f2bf(v.w);
            *(ushort4*)(&XS[m * 72 + c4 * 4]) = o;
        }
        __syncthreads();

        #pragma unroll
        for (int ks = 0; ks < 64; ks += 32) {
            short8 a = *(const short8*)(&XS[(m_base + c) * 72 + ks + quad * 8]);
            #pragma unroll
            for (int nt = 0; nt < 16; nt++) {
                short8 bf = *(const short8*)(&WS[(nt * 16 + c) * 72 + ks + quad * 8]);
                acc[nt] = __builtin_amdgcn_mfma_f32_16x16x32_bf16(a, bf, acc[nt], 0, 0, 0);
            }
        }
    }

    // epilogue: bias + LayerNorm + gamma/beta + gate
    float gc[16], ec[16];
    #pragma unroll
    for (int nt = 0; nt < 16; nt++) {
        int col = nt * 16 + c;
        float bi = PB[col];
        gc[nt] = PG[col]; ec[nt] = PE[col];
        #pragma unroll
        for (int r = 0; r < 4; r++) acc[nt][r] += bi;
    }

    float mu[4], rs[4];
    #pragma unroll
    for (int r = 0; r < 4; r++) {
        float s1 = 0.f, s2 = 0.f;
        #pragma unroll
        for (int nt = 0; nt < 16; nt++) { float v = acc[nt][r]; s1 += v; s2 += v * v; }
        #pragma unroll
        for (int ofs = 1; ofs < 16; ofs <<= 1) {
            s1 += __shfl_xor(s1, ofs);
            s2 += __shfl_xor(s2, ofs);
        }
        float m = s1 * (1.0f / 256.0f);
        float var = s2 * (1.0f / 256.0f) - m * m;
        mu[r] = m;
        rs[r] = rsqrtf(var + 1e-5f);
    }

    size_t obase = (size_t)bid * (64 * 256);
    #pragma unroll
    for (int nt = 0; nt < 16; nt++) {
        int col = nt * 16 + c;
        #pragma unroll
        for (int r = 0; r < 4; r++) {
            int m = m_base + quad * 4 + r;
            float v = (acc[nt][r] - mu[r]) * rs[r] * gc[nt] + ec[nt];
            out[obase + (size_t)m * 256 + col] = v * gate;
        }
    }
}

extern "C" void kernel_launch(void* const* d_in, const int* in_sizes, int n_in,
                              void* d_out, int out_size, void* d_ws, size_t ws_size,
                              hipStream_t stream) {
    const float* query = (const float*)d_in[0];
    const float* summ  = (const float*)d_in[1];
    const float* templ = (const float*)d_in[2];
    const float* wproj = (const float*)d_in[3];
    const float* bias  = (const float*)d_in[4];
    const float* gam   = (const float*)d_in[5];
    const float* bet   = (const float*)d_in[6];
    const float* gl    = (const float*)d_in[7];
    float* out = (float*)d_out;

    char* ws = (char*)d_ws;
    float* sims          = (float*)ws;                    // 20,480,000 B
    int* tidx            = (int*)(ws + 20480000);         // 2 KB
    unsigned short* wbf  = (unsigned short*)(ws + 20482048); // 128 KB

    k_wconv<<<64, 256, 0, stream>>>(wproj, wbf);
    k_sims<<<157, 256, 0, stream>>>(query, summ, sims);
    k_topk<<<64, 256, 0, stream>>>(sims, tidx, gl, out);
    k_tok<<<512, 256, 0, stream>>>(templ, wbf, tidx, bias, gam, bet, gl, out);
}